// Round 2
// baseline (155.709 us; speedup 1.0000x reference)
//
#include <hip/hip_runtime.h>

typedef unsigned short u16;
typedef __attribute__((ext_vector_type(4))) float f32x4;
typedef __attribute__((ext_vector_type(8))) short bf16x8;
typedef __attribute__((ext_vector_type(4))) short bf16x4;
typedef __attribute__((ext_vector_type(4))) int i32x4;
typedef __attribute__((ext_vector_type(4))) unsigned short u16x4;

#define MFMA_16x16x32(a, b, c) __builtin_amdgcn_mfma_f32_16x16x32_bf16((a), (b), (c), 0, 0, 0)
#define MFMA_16x16x16(a, b, c) __builtin_amdgcn_mfma_f32_16x16x16bf16_1k((a), (b), (c), 0, 0, 0)

__device__ __forceinline__ u16 f2bf(float f) {
    unsigned u = __float_as_uint(f);
    u += 0x7fffu + ((u >> 16) & 1u);
    return (u16)(u >> 16);
}

// ---------------- pack x: plain fp32 -> bf16 cast (reshape view is free) ----------------
__global__ void pack_x_kernel(const float* __restrict__ x, u16* __restrict__ xb, int n4) {
    int i = blockIdx.x * blockDim.x + threadIdx.x;
    if (i < n4) {
        f32x4 v = ((const f32x4*)x)[i];
        u16x4 o;
        o.x = f2bf(v.x); o.y = f2bf(v.y); o.z = f2bf(v.z); o.w = f2bf(v.w);
        ((u16x4*)xb)[i] = o;
    }
}

// ---- pack QKV weights: out[j][c'] = W_t[2*(c'&511)+(c'>>9)][j&511], t=j>>9, N-major bf16 ----
__global__ void pack_wqkv_kernel(const float* __restrict__ Wq, const float* __restrict__ Wk,
                                 const float* __restrict__ Wv, u16* __restrict__ out) {
    __shared__ u16 tile[64][65];
    int c0 = blockIdx.x * 64;      // c' block (K dim, 0..1023)
    int j0 = blockIdx.y * 64;      // j block (N dim, 0..1535)
    int tgt = j0 >> 9;
    int jj0 = j0 & 511;
    const float* W = (tgt == 0) ? Wq : (tgt == 1) ? Wk : Wv;
    int tx = threadIdx.x & 63, tq = threadIdx.x >> 6;
#pragma unroll
    for (int p = 0; p < 16; ++p) {
        int cl = p * 4 + tq;
        int c = c0 + cl;
        int srcRow = 2 * (c & 511) + (c >> 9);
        tile[cl][tx] = f2bf(W[(size_t)srcRow * 512 + jj0 + tx]);
    }
    __syncthreads();
#pragma unroll
    for (int p = 0; p < 16; ++p) {
        int jl = p * 4 + tq;
        out[(size_t)(j0 + jl) * 1024 + c0 + tx] = tile[tx][jl];
    }
}

// ---- pack Wo: out[j][k] = Wo[k][j], bf16, N-major ----
__global__ void pack_wo_kernel(const float* __restrict__ Wo, u16* __restrict__ out) {
    __shared__ u16 tile[64][65];
    int k0 = blockIdx.x * 64;
    int j0 = blockIdx.y * 64;
    int tx = threadIdx.x & 63, tq = threadIdx.x >> 6;
#pragma unroll
    for (int p = 0; p < 16; ++p) {
        int kl = p * 4 + tq;
        tile[kl][tx] = f2bf(Wo[(size_t)(k0 + kl) * 512 + j0 + tx]);
    }
    __syncthreads();
#pragma unroll
    for (int p = 0; p < 16; ++p) {
        int jl = p * 4 + tq;
        out[(size_t)(j0 + jl) * 512 + k0 + tx] = tile[tx][jl];
    }
}

// ---------------- GEMM: C[M][N] = A[M][K](bf16) @ Bt[N][K](bf16)^T + bias ----------------
// EPI 0: write fp32 out[m*N+col] + b0[col]
// EPI 1: QKV scatter: col -> (t,h,dd); out bf16 [t][(n*8+h)*2048+lseq][dd]
template <int EPI>
__global__ __launch_bounds__(256, 2) void gemm_kernel(
    const u16* __restrict__ A, const u16* __restrict__ Bt, int M, int N, int K,
    const float* __restrict__ b0, const float* __restrict__ b1, const float* __restrict__ b2,
    float* __restrict__ outF, u16* __restrict__ outQKV) {
    __shared__ __align__(16) char lds[128 * 64 * 2 * 2];
    char* ldsA = lds;
    char* ldsB = lds + 128 * 64 * 2;
    int t = threadIdx.x;
    int bm = blockIdx.x * 128, bn = blockIdx.y * 128;
    int w = t >> 6, lane = t & 63, g = lane >> 4, q = lane & 15;
    int wr = (w >> 1) * 64, wc = (w & 1) * 64;
    f32x4 acc[4][4] = {};

    for (int k0 = 0; k0 < K; k0 += 64) {
        __syncthreads();
#pragma unroll
        for (int p = 0; p < 4; ++p) {
            int row = p * 32 + (t >> 3);
            int slot = t & 7;
            int sw = ((slot ^ (row & 7)) << 4);
            *(i32x4*)(ldsA + row * 128 + sw) =
                *(const i32x4*)(A + (size_t)(bm + row) * K + k0 + slot * 8);
            *(i32x4*)(ldsB + row * 128 + sw) =
                *(const i32x4*)(Bt + (size_t)(bn + row) * K + k0 + slot * 8);
        }
        __syncthreads();
#pragma unroll
        for (int ks = 0; ks < 2; ++ks) {
            bf16x8 af[4], bfr[4];
#pragma unroll
            for (int i = 0; i < 4; ++i) {
                int row = wr + i * 16 + q;
                int slot = ks * 4 + g;
                af[i] = *(const bf16x8*)(ldsA + row * 128 + ((slot ^ (row & 7)) << 4));
                int col = wc + i * 16 + q;
                bfr[i] = *(const bf16x8*)(ldsB + col * 128 + ((slot ^ (col & 7)) << 4));
            }
#pragma unroll
            for (int i = 0; i < 4; ++i)
#pragma unroll
                for (int j = 0; j < 4; ++j)
                    acc[i][j] = MFMA_16x16x32(af[i], bfr[j], acc[i][j]);
        }
    }

#pragma unroll
    for (int i = 0; i < 4; ++i) {
#pragma unroll
        for (int j = 0; j < 4; ++j) {
            int col = bn + wc + j * 16 + q;
#pragma unroll
            for (int r = 0; r < 4; ++r) {
                int m = bm + wr + i * 16 + g * 4 + r;
                float v = acc[i][j][r];
                if (EPI == 0) {
                    outF[(size_t)m * N + col] = v + b0[col];
                } else {
                    int tt = col >> 9, jj = col & 511;
                    const float* bb = (tt == 0) ? b0 : (tt == 1) ? b1 : b2;
                    v += bb[jj];
                    int h = jj >> 6, dd = jj & 63;
                    int nb = m >> 11, lseq = m & 2047;
                    size_t dst = (size_t)tt * 2097152 +
                                 ((size_t)((nb * 8 + h) * 2048 + lseq)) * 64 + dd;
                    outQKV[dst] = f2bf(v);
                }
            }
        }
    }
}

// ---------------- flash attention: swapped QK^T, per-lane-column softmax ----------------
// grid (L/64, n*h); 4 waves/block; each wave: 16 q-rows, K tiles of 64.
__global__ __launch_bounds__(256, 2) void attn_kernel(
    const u16* __restrict__ Qb, const u16* __restrict__ Kb, const u16* __restrict__ Vb,
    u16* __restrict__ Ob) {
    int qb = blockIdx.x;
    int nh = blockIdx.y;
    int w = threadIdx.x >> 6, lane = threadIdx.x & 63;
    int g = lane >> 4, q = lane & 15;
    int q0 = qb * 64 + w * 16;
    int q_abs = q0 + q;
    const u16* Qp = Qb + (size_t)nh * 2048 * 64;
    const u16* Kp = Kb + (size_t)nh * 2048 * 64;
    const u16* Vp = Vb + (size_t)nh * 2048 * 64;
    const float SCALE = 0.044194173824159216f;  // 512^-0.5

    bf16x8 qf[2];
#pragma unroll
    for (int ks = 0; ks < 2; ++ks)
        qf[ks] = *(const bf16x8*)(Qp + (size_t)(q0 + q) * 64 + ks * 32 + g * 8);

    float m_run = -1e30f, l_run = 0.f;
    f32x4 ot[4] = {};

    for (int kt = 0; kt <= qb; ++kt) {
        // S' = K_tile @ Q^T : lane holds S'[k = kc*16 + g*4 + r][q = lane&15]
        f32x4 s[4] = {};
#pragma unroll
        for (int kc = 0; kc < 4; ++kc) {
#pragma unroll
            for (int ks = 0; ks < 2; ++ks) {
                bf16x8 kf = *(const bf16x8*)(Kp + (size_t)(kt * 64 + kc * 16 + q) * 64 +
                                             ks * 32 + g * 8);
                s[kc] = MFMA_16x16x32(kf, qf[ks], s[kc]);
            }
        }
        bool diag = (kt == qb);
        float sv[4][4];
        float pm = -1e30f;
#pragma unroll
        for (int kc = 0; kc < 4; ++kc) {
#pragma unroll
            for (int r = 0; r < 4; ++r) {
                float xv = s[kc][r] * SCALE;
                if (diag && (kt * 64 + kc * 16 + g * 4 + r > q_abs)) xv = -1e30f;
                sv[kc][r] = xv;
                pm = fmaxf(pm, xv);
            }
        }
        pm = fmaxf(pm, __shfl_xor(pm, 16, 64));
        pm = fmaxf(pm, __shfl_xor(pm, 32, 64));
        float mnew = fmaxf(m_run, pm);
        float alpha = __expf(m_run - mnew);
        float psum = 0.f;
        bf16x4 pf[4];
#pragma unroll
        for (int kc = 0; kc < 4; ++kc) {
#pragma unroll
            for (int r = 0; r < 4; ++r) {
                float pv = __expf(sv[kc][r] - mnew);
                psum += pv;
                pf[kc][r] = (short)f2bf(pv);
            }
        }
        psum += __shfl_xor(psum, 16, 64);
        psum += __shfl_xor(psum, 32, 64);
        l_run = l_run * alpha + psum;
        m_run = mnew;
#pragma unroll
        for (int hdg = 0; hdg < 4; ++hdg) ot[hdg] *= alpha;

        // O^T += V^T @ P : A-frag = V (hd = lane&15, k = g*4+j), B-frag = P
#pragma unroll
        for (int hdg = 0; hdg < 4; ++hdg) {
#pragma unroll
            for (int kc = 0; kc < 4; ++kc) {
                bf16x4 vf;
#pragma unroll
                for (int j = 0; j < 4; ++j)
                    vf[j] = (short)Vp[(size_t)(kt * 64 + kc * 16 + g * 4 + j) * 64 +
                                      hdg * 16 + q];
                ot[hdg] = MFMA_16x16x16(vf, pf[kc], ot[hdg]);
            }
        }
    }

    float inv_l = 1.f / l_run;
    int nb = nh >> 3, h = nh & 7;
#pragma unroll
    for (int hdg = 0; hdg < 4; ++hdg) {
        u16x4 wv;
#pragma unroll
        for (int r = 0; r < 4; ++r) wv[r] = f2bf(ot[hdg][r] * inv_l);
        *(u16x4*)(Ob + ((size_t)(nb * 2048 + q_abs) * 8 + h) * 64 + hdg * 16 + g * 4) = wv;
    }
}

extern "C" void kernel_launch(void* const* d_in, const int* in_sizes, int n_in,
                              void* d_out, int out_size, void* d_ws, size_t ws_size,
                              hipStream_t stream) {
    const float* x = (const float*)d_in[0];
    const float* Wq = (const float*)d_in[1];
    const float* bq = (const float*)d_in[2];
    const float* Wk = (const float*)d_in[3];
    const float* bk = (const float*)d_in[4];
    const float* Wv = (const float*)d_in[5];
    const float* bv = (const float*)d_in[6];
    const float* Wo = (const float*)d_in[7];
    const float* bo = (const float*)d_in[8];
    float* out = (float*)d_out;

    char* ws = (char*)d_ws;
    u16* xb = (u16*)ws;                              // 8 MB, [4096][1024]; reused as Ob
    u16* Wqkv_t = (u16*)(ws + 8388608);              // 3 MB, [1536][1024]
    u16* Wot = (u16*)(ws + 8388608 + 3145728);       // 0.5 MB, [512][512]
    u16* Qb = (u16*)(ws + 8388608 + 3145728 + 524288);  // 3x4 MB contiguous Q,K,V
    u16* Kb = Qb + 2097152;
    u16* Vb = Kb + 2097152;
    u16* Ob = xb;  // xb is dead after the QKV GEMM

    pack_x_kernel<<<4096, 256, 0, stream>>>(x, xb, 1048576);
    pack_wqkv_kernel<<<dim3(16, 24), 256, 0, stream>>>(Wq, Wk, Wv, Wqkv_t);
    pack_wo_kernel<<<dim3(8, 8), 256, 0, stream>>>(Wo, Wot);
    gemm_kernel<1><<<dim3(32, 12), 256, 0, stream>>>(xb, Wqkv_t, 4096, 1536, 1024,
                                                     bq, bk, bv, nullptr, Qb);
    attn_kernel<<<dim3(32, 16), 256, 0, stream>>>(Qb, Kb, Vb, Ob);
    gemm_kernel<0><<<dim3(32, 4), 256, 0, stream>>>(Ob, Wot, 4096, 512, 512,
                                                    bo, nullptr, nullptr, out, nullptr);
}

// Round 3
// 153.405 us; speedup vs baseline: 1.0150x; 1.0150x over previous
//
#include <hip/hip_runtime.h>

typedef unsigned short u16;
typedef __attribute__((ext_vector_type(4))) float f32x4;
typedef __attribute__((ext_vector_type(8))) short bf16x8;
typedef __attribute__((ext_vector_type(4))) short bf16x4;
typedef __attribute__((ext_vector_type(4))) int i32x4;
typedef __attribute__((ext_vector_type(4))) unsigned short u16x4;

#define MFMA_16x16x32(a, b, c) __builtin_amdgcn_mfma_f32_16x16x32_bf16((a), (b), (c), 0, 0, 0)
#define MFMA_16x16x16(a, b, c) __builtin_amdgcn_mfma_f32_16x16x16bf16_1k((a), (b), (c), 0, 0, 0)

__device__ __forceinline__ u16 f2bf(float f) {
    unsigned u = __float_as_uint(f);
    u += 0x7fffu + ((u >> 16) & 1u);
    return (u16)(u >> 16);
}

// ---------------- pack x: plain fp32 -> bf16 cast (reshape view is free) ----------------
__global__ void pack_x_kernel(const float* __restrict__ x, u16* __restrict__ xb, int n4) {
    int i = blockIdx.x * blockDim.x + threadIdx.x;
    if (i < n4) {
        f32x4 v = ((const f32x4*)x)[i];
        u16x4 o;
        o.x = f2bf(v.x); o.y = f2bf(v.y); o.z = f2bf(v.z); o.w = f2bf(v.w);
        ((u16x4*)xb)[i] = o;
    }
}

// ---- pack QKV weights: out[j][c'] = W_t[2*(c'&511)+(c'>>9)][j&511], t=j>>9, N-major bf16 ----
__global__ void pack_wqkv_kernel(const float* __restrict__ Wq, const float* __restrict__ Wk,
                                 const float* __restrict__ Wv, u16* __restrict__ out) {
    __shared__ u16 tile[64][65];
    int c0 = blockIdx.x * 64;      // c' block (K dim, 0..1023)
    int j0 = blockIdx.y * 64;      // j block (N dim, 0..1535)
    int tgt = j0 >> 9;
    int jj0 = j0 & 511;
    const float* W = (tgt == 0) ? Wq : (tgt == 1) ? Wk : Wv;
    int tx = threadIdx.x & 63, tq = threadIdx.x >> 6;
#pragma unroll
    for (int p = 0; p < 16; ++p) {
        int cl = p * 4 + tq;
        int c = c0 + cl;
        int srcRow = 2 * (c & 511) + (c >> 9);
        tile[cl][tx] = f2bf(W[(size_t)srcRow * 512 + jj0 + tx]);
    }
    __syncthreads();
#pragma unroll
    for (int p = 0; p < 16; ++p) {
        int jl = p * 4 + tq;
        out[(size_t)(j0 + jl) * 1024 + c0 + tx] = tile[tx][jl];
    }
}

// ---- pack Wo: out[j][k] = Wo[k][j], bf16, N-major ----
__global__ void pack_wo_kernel(const float* __restrict__ Wo, u16* __restrict__ out) {
    __shared__ u16 tile[64][65];
    int k0 = blockIdx.x * 64;
    int j0 = blockIdx.y * 64;
    int tx = threadIdx.x & 63, tq = threadIdx.x >> 6;
#pragma unroll
    for (int p = 0; p < 16; ++p) {
        int kl = p * 4 + tq;
        tile[kl][tx] = f2bf(Wo[(size_t)(k0 + kl) * 512 + j0 + tx]);
    }
    __syncthreads();
#pragma unroll
    for (int p = 0; p < 16; ++p) {
        int jl = p * 4 + tq;
        out[(size_t)(j0 + jl) * 512 + k0 + tx] = tile[tx][jl];
    }
}

// ---------------- GEMM: C[M][N] = A[M][K](bf16) @ Bt[N][K](bf16)^T + bias ----------------
// EPI 0: write fp32 out[m*N+col] + b0[col]
// EPI 1: QKV scatter: Q,K -> bf16 [t][(n*8+h)*2048+lseq][dd]; V -> TRANSPOSED [(n*8+h)*64+dd][lseq]
template <int EPI>
__global__ __launch_bounds__(256, 2) void gemm_kernel(
    const u16* __restrict__ A, const u16* __restrict__ Bt, int M, int N, int K,
    const float* __restrict__ b0, const float* __restrict__ b1, const float* __restrict__ b2,
    float* __restrict__ outF, u16* __restrict__ outQKV) {
    __shared__ __align__(16) char lds[128 * 64 * 2 * 2];
    char* ldsA = lds;
    char* ldsB = lds + 128 * 64 * 2;
    int t = threadIdx.x;
    int bm = blockIdx.x * 128, bn = blockIdx.y * 128;
    int w = t >> 6, lane = t & 63, g = lane >> 4, q = lane & 15;
    int wr = (w >> 1) * 64, wc = (w & 1) * 64;
    f32x4 acc[4][4] = {};

    for (int k0 = 0; k0 < K; k0 += 64) {
        __syncthreads();
#pragma unroll
        for (int p = 0; p < 4; ++p) {
            int row = p * 32 + (t >> 3);
            int slot = t & 7;
            int sw = ((slot ^ (row & 7)) << 4);
            *(i32x4*)(ldsA + row * 128 + sw) =
                *(const i32x4*)(A + (size_t)(bm + row) * K + k0 + slot * 8);
            *(i32x4*)(ldsB + row * 128 + sw) =
                *(const i32x4*)(Bt + (size_t)(bn + row) * K + k0 + slot * 8);
        }
        __syncthreads();
#pragma unroll
        for (int ks = 0; ks < 2; ++ks) {
            bf16x8 af[4], bfr[4];
#pragma unroll
            for (int i = 0; i < 4; ++i) {
                int row = wr + i * 16 + q;
                int slot = ks * 4 + g;
                af[i] = *(const bf16x8*)(ldsA + row * 128 + ((slot ^ (row & 7)) << 4));
                int col = wc + i * 16 + q;
                bfr[i] = *(const bf16x8*)(ldsB + col * 128 + ((slot ^ (col & 7)) << 4));
            }
#pragma unroll
            for (int i = 0; i < 4; ++i)
#pragma unroll
                for (int j = 0; j < 4; ++j)
                    acc[i][j] = MFMA_16x16x32(af[i], bfr[j], acc[i][j]);
        }
    }

#pragma unroll
    for (int i = 0; i < 4; ++i) {
#pragma unroll
        for (int j = 0; j < 4; ++j) {
            int col = bn + wc + j * 16 + q;
#pragma unroll
            for (int r = 0; r < 4; ++r) {
                int m = bm + wr + i * 16 + g * 4 + r;
                float v = acc[i][j][r];
                if (EPI == 0) {
                    outF[(size_t)m * N + col] = v + b0[col];
                } else {
                    int tt = col >> 9, jj = col & 511;
                    const float* bb = (tt == 0) ? b0 : (tt == 1) ? b1 : b2;
                    v += bb[jj];
                    int h = jj >> 6, dd = jj & 63;
                    int nb = m >> 11, lseq = m & 2047;
                    size_t dst;
                    if (tt == 2) {
                        // V transposed: [(nb*8+h)*64 + dd][lseq]
                        dst = (size_t)2 * 2097152 +
                              ((size_t)((nb * 8 + h) * 64 + dd)) * 2048 + lseq;
                    } else {
                        dst = (size_t)tt * 2097152 +
                              ((size_t)((nb * 8 + h) * 2048 + lseq)) * 64 + dd;
                    }
                    outQKV[dst] = f2bf(v);
                }
            }
        }
    }
}

// ---------------- flash attention: 1 wave/block, 16 q-rows/wave ----------------
// grid (nh=16, 128 q-tiles reversed); swapped QK^T, per-lane-column softmax.
// V is pre-transposed: Vt[nh][hd=64][k=2048] so PV A-frags are contiguous 8B loads.
__global__ __launch_bounds__(64) void attn_kernel(
    const u16* __restrict__ Qb, const u16* __restrict__ Kb, const u16* __restrict__ Vt,
    u16* __restrict__ Ob) {
    int nh = blockIdx.x;
    int qt = gridDim.y - 1 - blockIdx.y;  // longest blocks first
    int lane = threadIdx.x & 63;
    int g = lane >> 4, q = lane & 15;
    int q0 = qt * 16, q_abs = q0 + q;
    const u16* Qp = Qb + (size_t)nh * 131072;
    const u16* Kp = Kb + (size_t)nh * 131072;
    const u16* Vp = Vt + (size_t)nh * 131072;
    const float SCALE = 0.044194173824159216f;  // 512^-0.5

    bf16x8 qf[2];
#pragma unroll
    for (int ks = 0; ks < 2; ++ks)
        qf[ks] = *(const bf16x8*)(Qp + (size_t)q_abs * 64 + ks * 32 + g * 8);

    float m_run = -1e30f, l_run = 0.f;
    f32x4 ot[4] = {};
    int nkt = (q0 >> 6) + 1;

    // prefetch K tile 0
    bf16x8 kf[8];
#pragma unroll
    for (int kc = 0; kc < 4; ++kc)
#pragma unroll
        for (int ks = 0; ks < 2; ++ks)
            kf[kc * 2 + ks] =
                *(const bf16x8*)(Kp + (size_t)(kc * 16 + q) * 64 + ks * 32 + g * 8);

    for (int kt = 0; kt < nkt; ++kt) {
        // S' = K_tile @ Q^T : lane holds S'[k = kc*16 + g*4 + r][q]
        f32x4 s[4] = {};
#pragma unroll
        for (int kc = 0; kc < 4; ++kc)
#pragma unroll
            for (int ks = 0; ks < 2; ++ks)
                s[kc] = MFMA_16x16x32(kf[kc * 2 + ks], qf[ks], s[kc]);

        // issue V loads for this tile (needed after softmax)
        bf16x4 vf[16];
#pragma unroll
        for (int hdg = 0; hdg < 4; ++hdg)
#pragma unroll
            for (int kc = 0; kc < 4; ++kc)
                vf[hdg * 4 + kc] = *(const bf16x4*)(
                    Vp + (size_t)(hdg * 16 + q) * 2048 + kt * 64 + kc * 16 + g * 4);

        // prefetch next K tile (latency hides under softmax VALU)
        int ktn = (kt + 1 < nkt) ? kt + 1 : kt;
        bf16x8 kfn[8];
#pragma unroll
        for (int kc = 0; kc < 4; ++kc)
#pragma unroll
            for (int ks = 0; ks < 2; ++ks)
                kfn[kc * 2 + ks] = *(const bf16x8*)(
                    Kp + (size_t)(ktn * 64 + kc * 16 + q) * 64 + ks * 32 + g * 8);

        bool diag = (kt == nkt - 1);
        float sv[4][4];
        float pm = -1e30f;
#pragma unroll
        for (int kc = 0; kc < 4; ++kc) {
#pragma unroll
            for (int r = 0; r < 4; ++r) {
                float xv = s[kc][r] * SCALE;
                if (diag && (kt * 64 + kc * 16 + g * 4 + r > q_abs)) xv = -1e30f;
                sv[kc][r] = xv;
                pm = fmaxf(pm, xv);
            }
        }
        pm = fmaxf(pm, __shfl_xor(pm, 16, 64));
        pm = fmaxf(pm, __shfl_xor(pm, 32, 64));
        float mnew = fmaxf(m_run, pm);
        float alpha = __expf(m_run - mnew);
        float psum = 0.f;
        bf16x4 pf[4];
#pragma unroll
        for (int kc = 0; kc < 4; ++kc) {
#pragma unroll
            for (int r = 0; r < 4; ++r) {
                float pv = __expf(sv[kc][r] - mnew);
                psum += pv;
                pf[kc][r] = (short)f2bf(pv);
            }
        }
        psum += __shfl_xor(psum, 16, 64);
        psum += __shfl_xor(psum, 32, 64);
        l_run = l_run * alpha + psum;
        m_run = mnew;
#pragma unroll
        for (int hdg = 0; hdg < 4; ++hdg) ot[hdg] *= alpha;

        // O^T += V^T @ P : A-frag = Vt rows (hd = lane&15, k = g*4+j), B-frag = P
#pragma unroll
        for (int hdg = 0; hdg < 4; ++hdg)
#pragma unroll
            for (int kc = 0; kc < 4; ++kc)
                ot[hdg] = MFMA_16x16x16(vf[hdg * 4 + kc], pf[kc], ot[hdg]);

#pragma unroll
        for (int i = 0; i < 8; ++i) kf[i] = kfn[i];
    }

    float inv_l = 1.f / l_run;
    int nb = nh >> 3, h = nh & 7;
#pragma unroll
    for (int hdg = 0; hdg < 4; ++hdg) {
        u16x4 wv;
#pragma unroll
        for (int r = 0; r < 4; ++r) wv[r] = f2bf(ot[hdg][r] * inv_l);
        *(u16x4*)(Ob + ((size_t)(nb * 2048 + q_abs) * 8 + h) * 64 + hdg * 16 + g * 4) = wv;
    }
}

extern "C" void kernel_launch(void* const* d_in, const int* in_sizes, int n_in,
                              void* d_out, int out_size, void* d_ws, size_t ws_size,
                              hipStream_t stream) {
    const float* x = (const float*)d_in[0];
    const float* Wq = (const float*)d_in[1];
    const float* bq = (const float*)d_in[2];
    const float* Wk = (const float*)d_in[3];
    const float* bk = (const float*)d_in[4];
    const float* Wv = (const float*)d_in[5];
    const float* bv = (const float*)d_in[6];
    const float* Wo = (const float*)d_in[7];
    const float* bo = (const float*)d_in[8];
    float* out = (float*)d_out;

    char* ws = (char*)d_ws;
    u16* xb = (u16*)ws;                              // 8 MB, [4096][1024]; reused as Ob
    u16* Wqkv_t = (u16*)(ws + 8388608);              // 3 MB, [1536][1024]
    u16* Wot = (u16*)(ws + 8388608 + 3145728);       // 0.5 MB, [512][512]
    u16* Qb = (u16*)(ws + 8388608 + 3145728 + 524288);  // 3x4 MB contiguous Q,K,Vt
    u16* Kb = Qb + 2097152;
    u16* Vt = Kb + 2097152;
    u16* Ob = xb;  // xb is dead after the QKV GEMM

    pack_x_kernel<<<4096, 256, 0, stream>>>(x, xb, 1048576);
    pack_wqkv_kernel<<<dim3(16, 24), 256, 0, stream>>>(Wq, Wk, Wv, Wqkv_t);
    pack_wo_kernel<<<dim3(8, 8), 256, 0, stream>>>(Wo, Wot);
    gemm_kernel<1><<<dim3(32, 12), 256, 0, stream>>>(xb, Wqkv_t, 4096, 1536, 1024,
                                                     bq, bk, bv, nullptr, Qb);
    attn_kernel<<<dim3(16, 128), 64, 0, stream>>>(Qb, Kb, Vt, Ob);
    gemm_kernel<0><<<dim3(32, 4), 256, 0, stream>>>(Ob, Wot, 4096, 512, 512,
                                                    bo, nullptr, nullptr, out, nullptr);
}

// Round 4
// 132.635 us; speedup vs baseline: 1.1740x; 1.1566x over previous
//
#include <hip/hip_runtime.h>

typedef unsigned short u16;
typedef __attribute__((ext_vector_type(4))) float f32x4;
typedef __attribute__((ext_vector_type(8))) short bf16x8;
typedef __attribute__((ext_vector_type(4))) short bf16x4;
typedef __attribute__((ext_vector_type(4))) int i32x4;
typedef __attribute__((ext_vector_type(4))) unsigned short u16x4;

#define MFMA_16x16x32(a, b, c) __builtin_amdgcn_mfma_f32_16x16x32_bf16((a), (b), (c), 0, 0, 0)
#define NSPLIT 4

__device__ __forceinline__ u16 f2bf(float f) {
    unsigned u = __float_as_uint(f);
    u += 0x7fffu + ((u >> 16) & 1u);
    return (u16)(u >> 16);
}

__device__ __forceinline__ unsigned cvt_pk_bf16(float lo, float hi) {
    unsigned r;
    asm("v_cvt_pk_bf16_f32 %0, %1, %2" : "=v"(r) : "v"(lo), "v"(hi));
    return r;
}

// ---------------- pack x: plain fp32 -> bf16 cast (reshape view is free) ----------------
__global__ void pack_x_kernel(const float* __restrict__ x, u16* __restrict__ xb, int n4) {
    int i = blockIdx.x * blockDim.x + threadIdx.x;
    if (i < n4) {
        f32x4 v = ((const f32x4*)x)[i];
        u16x4 o;
        o.x = f2bf(v.x); o.y = f2bf(v.y); o.z = f2bf(v.z); o.w = f2bf(v.w);
        ((u16x4*)xb)[i] = o;
    }
}

// ---- pack QKV weights: out[j][c'] = W_t[2*(c'&511)+(c'>>9)][j&511], t=j>>9, N-major bf16 ----
__global__ void pack_wqkv_kernel(const float* __restrict__ Wq, const float* __restrict__ Wk,
                                 const float* __restrict__ Wv, u16* __restrict__ out) {
    __shared__ u16 tile[64][65];
    int c0 = blockIdx.x * 64;      // c' block (K dim, 0..1023)
    int j0 = blockIdx.y * 64;      // j block (N dim, 0..1535)
    int tgt = j0 >> 9;
    int jj0 = j0 & 511;
    const float* W = (tgt == 0) ? Wq : (tgt == 1) ? Wk : Wv;
    int tx = threadIdx.x & 63, tq = threadIdx.x >> 6;
#pragma unroll
    for (int p = 0; p < 16; ++p) {
        int cl = p * 4 + tq;
        int c = c0 + cl;
        int srcRow = 2 * (c & 511) + (c >> 9);
        tile[cl][tx] = f2bf(W[(size_t)srcRow * 512 + jj0 + tx]);
    }
    __syncthreads();
#pragma unroll
    for (int p = 0; p < 16; ++p) {
        int jl = p * 4 + tq;
        out[(size_t)(j0 + jl) * 1024 + c0 + tx] = tile[tx][jl];
    }
}

// ---- pack Wo: out[j][k] = Wo[k][j], bf16, N-major ----
__global__ void pack_wo_kernel(const float* __restrict__ Wo, u16* __restrict__ out) {
    __shared__ u16 tile[64][65];
    int k0 = blockIdx.x * 64;
    int j0 = blockIdx.y * 64;
    int tx = threadIdx.x & 63, tq = threadIdx.x >> 6;
#pragma unroll
    for (int p = 0; p < 16; ++p) {
        int kl = p * 4 + tq;
        tile[kl][tx] = f2bf(Wo[(size_t)(k0 + kl) * 512 + j0 + tx]);
    }
    __syncthreads();
#pragma unroll
    for (int p = 0; p < 16; ++p) {
        int jl = p * 4 + tq;
        out[(size_t)(j0 + jl) * 512 + k0 + tx] = tile[tx][jl];
    }
}

// ---------------- GEMM: C[M][N] = A[M][K](bf16) @ Bt[N][K](bf16)^T + bias ----------------
// EPI 0: write fp32 out[m*N+col] + b0[col]
// EPI 1: QKV scatter: Q,K -> bf16 [t][(n*8+h)*2048+lseq][dd];
//        V -> transposed + k-permuted: [(n*8+h)*64+dd][perm(lseq)]
template <int EPI>
__global__ __launch_bounds__(256, 2) void gemm_kernel(
    const u16* __restrict__ A, const u16* __restrict__ Bt, int M, int N, int K,
    const float* __restrict__ b0, const float* __restrict__ b1, const float* __restrict__ b2,
    float* __restrict__ outF, u16* __restrict__ outQKV) {
    __shared__ __align__(16) char lds[128 * 64 * 2 * 2];
    char* ldsA = lds;
    char* ldsB = lds + 128 * 64 * 2;
    int t = threadIdx.x;
    int bm = blockIdx.x * 128, bn = blockIdx.y * 128;
    int w = t >> 6, lane = t & 63, g = lane >> 4, q = lane & 15;
    int wr = (w >> 1) * 64, wc = (w & 1) * 64;
    f32x4 acc[4][4] = {};

    for (int k0 = 0; k0 < K; k0 += 64) {
        __syncthreads();
#pragma unroll
        for (int p = 0; p < 4; ++p) {
            int row = p * 32 + (t >> 3);
            int slot = t & 7;
            int sw = ((slot ^ (row & 7)) << 4);
            *(i32x4*)(ldsA + row * 128 + sw) =
                *(const i32x4*)(A + (size_t)(bm + row) * K + k0 + slot * 8);
            *(i32x4*)(ldsB + row * 128 + sw) =
                *(const i32x4*)(Bt + (size_t)(bn + row) * K + k0 + slot * 8);
        }
        __syncthreads();
#pragma unroll
        for (int ks = 0; ks < 2; ++ks) {
            bf16x8 af[4], bfr[4];
#pragma unroll
            for (int i = 0; i < 4; ++i) {
                int row = wr + i * 16 + q;
                int slot = ks * 4 + g;
                af[i] = *(const bf16x8*)(ldsA + row * 128 + ((slot ^ (row & 7)) << 4));
                int col = wc + i * 16 + q;
                bfr[i] = *(const bf16x8*)(ldsB + col * 128 + ((slot ^ (col & 7)) << 4));
            }
#pragma unroll
            for (int i = 0; i < 4; ++i)
#pragma unroll
                for (int j = 0; j < 4; ++j)
                    acc[i][j] = MFMA_16x16x32(af[i], bfr[j], acc[i][j]);
        }
    }

#pragma unroll
    for (int i = 0; i < 4; ++i) {
#pragma unroll
        for (int j = 0; j < 4; ++j) {
            int col = bn + wc + j * 16 + q;
#pragma unroll
            for (int r = 0; r < 4; ++r) {
                int m = bm + wr + i * 16 + g * 4 + r;
                float v = acc[i][j][r];
                if (EPI == 0) {
                    outF[(size_t)m * N + col] = v + b0[col];
                } else {
                    int tt = col >> 9, jj = col & 511;
                    const float* bb = (tt == 0) ? b0 : (tt == 1) ? b1 : b2;
                    v += bb[jj];
                    int h = jj >> 6, dd = jj & 63;
                    int nb = m >> 11, lseq = m & 2047;
                    size_t dst;
                    if (tt == 2) {
                        // V transposed + in-tile k-permutation for PV x32 fragments:
                        // t6 = kc(2b) g(2b) r(2b) -> t6' = m(1b) g(2b) kc'(1b) r(2b)
                        int t6 = lseq & 63;
                        int t6p = (t6 & 0x20) | ((t6 & 0xC) << 1) | ((t6 & 0x10) >> 2) |
                                  (t6 & 3);
                        int lp = (lseq & ~63) | t6p;
                        dst = (size_t)2 * 2097152 +
                              ((size_t)((nb * 8 + h) * 64 + dd)) * 2048 + lp;
                    } else {
                        dst = (size_t)tt * 2097152 +
                              ((size_t)((nb * 8 + h) * 2048 + lseq)) * 64 + dd;
                    }
                    outQKV[dst] = f2bf(v);
                }
            }
        }
    }
}

// ---------------- flash attention, split-K: each wave does a K-chunk, writes partials ---
// grid (nh=16, 128 q-tiles reversed, NSPLIT); 1 wave/block, 16 q-rows/wave.
__global__ __launch_bounds__(64, 3) void attn_kernel(
    const u16* __restrict__ Qb, const u16* __restrict__ Kb, const u16* __restrict__ Vt,
    float* __restrict__ Opart, float* __restrict__ MLpart) {
    int nh = blockIdx.x;
    int qt = gridDim.y - 1 - blockIdx.y;  // longest blocks first
    int sp = blockIdx.z;
    int lane = threadIdx.x & 63;
    int g = lane >> 4, q = lane & 15;
    int q0 = qt * 16, q_abs = q0 + q;
    int nkt = (q0 >> 6) + 1;
    int cnt = (nkt + NSPLIT - 1) / NSPLIT;
    int k0t = sp * cnt;
    if (k0t >= nkt) return;
    int kend = k0t + cnt;
    if (kend > nkt) kend = nkt;

    const u16* Qp = Qb + (size_t)nh * 131072;
    const u16* Kp = Kb + (size_t)nh * 131072;
    const u16* Vp = Vt + (size_t)nh * 131072;
    const float SCALE = 0.044194173824159216f;  // 512^-0.5

    bf16x8 qf[2];
#pragma unroll
    for (int ks = 0; ks < 2; ++ks)
        qf[ks] = *(const bf16x8*)(Qp + (size_t)q_abs * 64 + ks * 32 + g * 8);

    float m_run = -1e30f, l_run = 0.f;
    f32x4 ot[4] = {};

    for (int kt = k0t; kt < kend; ++kt) {
        // issue all loads for this tile up front
        bf16x8 kf[8];
#pragma unroll
        for (int kc = 0; kc < 4; ++kc)
#pragma unroll
            for (int ks = 0; ks < 2; ++ks)
                kf[kc * 2 + ks] = *(const bf16x8*)(
                    Kp + (size_t)(kt * 64 + kc * 16 + q) * 64 + ks * 32 + g * 8);
        bf16x8 vf[8];
#pragma unroll
        for (int hdg = 0; hdg < 4; ++hdg)
#pragma unroll
            for (int mm = 0; mm < 2; ++mm)
                vf[hdg * 2 + mm] = *(const bf16x8*)(
                    Vp + (size_t)(hdg * 16 + q) * 2048 + kt * 64 + mm * 32 + g * 8);

        // S' = K_tile @ Q^T : lane holds S'[k = kc*16 + g*4 + r][q]
        f32x4 sacc[4] = {};
#pragma unroll
        for (int kc = 0; kc < 4; ++kc)
#pragma unroll
            for (int ks = 0; ks < 2; ++ks)
                sacc[kc] = MFMA_16x16x32(kf[kc * 2 + ks], qf[ks], sacc[kc]);

        float sv[4][4];
#pragma unroll
        for (int kc = 0; kc < 4; ++kc)
#pragma unroll
            for (int r = 0; r < 4; ++r) sv[kc][r] = sacc[kc][r] * SCALE;
        if (kt == nkt - 1) {  // wave-uniform diag masking
#pragma unroll
            for (int kc = 0; kc < 4; ++kc)
#pragma unroll
                for (int r = 0; r < 4; ++r)
                    if (kt * 64 + kc * 16 + g * 4 + r > q_abs) sv[kc][r] = -1e30f;
        }
        float pm = -1e30f;
#pragma unroll
        for (int kc = 0; kc < 4; ++kc)
#pragma unroll
            for (int r = 0; r < 4; ++r) pm = fmaxf(pm, sv[kc][r]);
        pm = fmaxf(pm, __shfl_xor(pm, 16, 64));
        pm = fmaxf(pm, __shfl_xor(pm, 32, 64));
        float mnew = fmaxf(m_run, pm);
        float alpha = __expf(m_run - mnew);
        float psum = 0.f;
        float pv[4][4];
#pragma unroll
        for (int kc = 0; kc < 4; ++kc)
#pragma unroll
            for (int r = 0; r < 4; ++r) {
                float p = __expf(sv[kc][r] - mnew);
                pv[kc][r] = p;
                psum += p;
            }
        psum += __shfl_xor(psum, 16, 64);
        psum += __shfl_xor(psum, 32, 64);
        l_run = l_run * alpha + psum;
        m_run = mnew;

        // pack P into x32 B-fragments: pfm[mm][j = kc'*4 + r] = pv[mm*2+kc'][r]
        bf16x8 pfm[2];
#pragma unroll
        for (int mm = 0; mm < 2; ++mm) {
            union { unsigned u[4]; bf16x8 v; } pk;
            pk.u[0] = cvt_pk_bf16(pv[2 * mm][0], pv[2 * mm][1]);
            pk.u[1] = cvt_pk_bf16(pv[2 * mm][2], pv[2 * mm][3]);
            pk.u[2] = cvt_pk_bf16(pv[2 * mm + 1][0], pv[2 * mm + 1][1]);
            pk.u[3] = cvt_pk_bf16(pv[2 * mm + 1][2], pv[2 * mm + 1][3]);
            pfm[mm] = pk.v;
        }

#pragma unroll
        for (int hdg = 0; hdg < 4; ++hdg) ot[hdg] *= alpha;
        // O^T += V^T @ P with K=32 MFMAs over permuted k
#pragma unroll
        for (int hdg = 0; hdg < 4; ++hdg)
#pragma unroll
            for (int mm = 0; mm < 2; ++mm)
                ot[hdg] = MFMA_16x16x32(vf[hdg * 2 + mm], pfm[mm], ot[hdg]);
    }

    size_t b = (size_t)(sp * 16 + nh) * 128 + qt;
#pragma unroll
    for (int hdg = 0; hdg < 4; ++hdg)
        *(f32x4*)(Opart + b * 1024 + hdg * 256 + lane * 4) = ot[hdg];
    if (g == 0) {
        MLpart[b * 32 + q * 2] = m_run;
        MLpart[b * 32 + q * 2 + 1] = l_run;
    }
}

// ---------------- combine split-K partials -> Ob (bf16, [n][l][h][d]) ----------------
__global__ __launch_bounds__(64) void attn_combine_kernel(
    const float* __restrict__ Opart, const float* __restrict__ MLpart,
    u16* __restrict__ Ob) {
    int nh = blockIdx.x, qt = blockIdx.y;
    int lane = threadIdx.x & 63;
    int g = lane >> 4, q = lane & 15;
    int nkt = ((qt * 16) >> 6) + 1;
    int cnt = (nkt + NSPLIT - 1) / NSPLIT;
    int nsp = (nkt + cnt - 1) / cnt;

    float ms[NSPLIT], ls[NSPLIT];
    float M = -1e30f;
    for (int s2 = 0; s2 < nsp; ++s2) {
        size_t b = (size_t)(s2 * 16 + nh) * 128 + qt;
        ms[s2] = MLpart[b * 32 + q * 2];
        ls[s2] = MLpart[b * 32 + q * 2 + 1];
        M = fmaxf(M, ms[s2]);
    }
    float L = 0.f;
    float al[NSPLIT];
    for (int s2 = 0; s2 < nsp; ++s2) {
        al[s2] = __expf(ms[s2] - M);
        L += ls[s2] * al[s2];
    }
    f32x4 of[4] = {};
    for (int s2 = 0; s2 < nsp; ++s2) {
        size_t b = (size_t)(s2 * 16 + nh) * 128 + qt;
#pragma unroll
        for (int hdg = 0; hdg < 4; ++hdg) {
            f32x4 o = *(const f32x4*)(Opart + b * 1024 + hdg * 256 + lane * 4);
            of[hdg] += o * al[s2];
        }
    }
    float invL = 1.f / L;
    int nb = nh >> 3, h = nh & 7, q_abs = qt * 16 + q;
#pragma unroll
    for (int hdg = 0; hdg < 4; ++hdg) {
        u16x4 wv;
#pragma unroll
        for (int r = 0; r < 4; ++r) wv[r] = f2bf(of[hdg][r] * invL);
        *(u16x4*)(Ob + ((size_t)(nb * 2048 + q_abs) * 8 + h) * 64 + hdg * 16 + g * 4) = wv;
    }
}

extern "C" void kernel_launch(void* const* d_in, const int* in_sizes, int n_in,
                              void* d_out, int out_size, void* d_ws, size_t ws_size,
                              hipStream_t stream) {
    const float* x = (const float*)d_in[0];
    const float* Wq = (const float*)d_in[1];
    const float* bq = (const float*)d_in[2];
    const float* Wk = (const float*)d_in[3];
    const float* bk = (const float*)d_in[4];
    const float* Wv = (const float*)d_in[5];
    const float* bv = (const float*)d_in[6];
    const float* Wo = (const float*)d_in[7];
    const float* bo = (const float*)d_in[8];
    float* out = (float*)d_out;

    char* ws = (char*)d_ws;
    u16* xb = (u16*)ws;                                 // 8 MB, [4096][1024]; reused as Ob
    u16* Wqkv_t = (u16*)(ws + 8388608);                 // 3 MB
    u16* Wot = (u16*)(ws + 8388608 + 3145728);          // 0.5 MB
    u16* Qb = (u16*)(ws + 8388608 + 3145728 + 524288);  // 3x4 MB contiguous Q,K,Vt
    u16* Kb = Qb + 2097152;
    u16* Vt = Kb + 2097152;
    u16* Ob = xb;                                       // xb dead after QKV GEMM
    float* Opart = (float*)(ws + 24641536);             // 32 MB split-K O partials
    float* MLpart = (float*)(ws + 24641536 + 33554432); // 1 MB m/l partials

    pack_x_kernel<<<4096, 256, 0, stream>>>(x, xb, 1048576);
    pack_wqkv_kernel<<<dim3(16, 24), 256, 0, stream>>>(Wq, Wk, Wv, Wqkv_t);
    pack_wo_kernel<<<dim3(8, 8), 256, 0, stream>>>(Wo, Wot);
    gemm_kernel<1><<<dim3(32, 12), 256, 0, stream>>>(xb, Wqkv_t, 4096, 1536, 1024,
                                                     bq, bk, bv, nullptr, Qb);
    attn_kernel<<<dim3(16, 128, NSPLIT), 64, 0, stream>>>(Qb, Kb, Vt, Opart, MLpart);
    attn_combine_kernel<<<dim3(16, 128), 64, 0, stream>>>(Opart, MLpart, Ob);
    gemm_kernel<0><<<dim3(32, 4), 256, 0, stream>>>(Ob, Wot, 4096, 512, 512,
                                                    bo, nullptr, nullptr, out, nullptr);
}